// Round 1
// baseline (23693.810 us; speedup 1.0000x reference)
//
#include <hip/hip_runtime.h>
#include <math.h>

#define BB 64
#define TT 512
#define FF 32
#define HH 512
#define OO 680

#define H1SZ (HH*BB)   // 32768
#define H2SZ (OO*BB)   // 43520

// ws layout (floats), ping-pong state buffers
#define H1_OFF 0
#define C1_OFF (H1_OFF + 2*H1SZ)
#define H2_OFF (C1_OFF + 2*H1SZ)
#define C2_OFF (H2_OFF + 2*H2SZ)
#define WS_FLOATS (C2_OFF + 2*H2SZ)   // 305152 floats = 1.22 MB

__global__ void zero_ws(float* ws) {
    int i = blockIdx.x * blockDim.x + threadIdx.x;
    if (i < WS_FLOATS) ws[i] = 0.f;
}

__device__ __forceinline__ float sigf(float x) { return 1.f / (1.f + expf(-x)); }

// ---- layer-2 compute: NC columns, 4 gates, K=1192 split 4 ways across waves ----
template<int NC>
__device__ __forceinline__ void phaseB_compute(
    int col0, int wv, int lane,
    const float* __restrict__ Wih2, const float* __restrict__ Whh2,
    const float* __restrict__ c1r, const float* __restrict__ h2r,
    float (*part)[3][4][BB])
{
    float acc[NC][4];
    #pragma unroll
    for (int c = 0; c < NC; ++c)
        #pragma unroll
        for (int g = 0; g < 4; ++g) acc[c][g] = 0.f;

    // wave K ranges: {0,300,600,896,1192} (sizes 300,300,296,296; all 4-aligned)
    const int k0 = (wv < 2) ? wv * 300 : 600 + (wv - 2) * 296;
    const int k1 = (wv == 0) ? 300 : (wv == 1) ? 600 : (wv == 2) ? 896 : 1192;

    // c1 segment: k in [k0, min(k1,512)); act c1r[k*BB+lane]; W_ih2[row*HH + k]
    {
        const int cb = (k1 < 512) ? k1 : 512;
        for (int k = k0; k < cb; k += 4) {
            float a0 = c1r[(k + 0) * BB + lane];
            float a1 = c1r[(k + 1) * BB + lane];
            float a2 = c1r[(k + 2) * BB + lane];
            float a3 = c1r[(k + 3) * BB + lane];
            #pragma unroll
            for (int c = 0; c < NC; ++c)
                #pragma unroll
                for (int g = 0; g < 4; ++g) {
                    const float4 w = *(const float4*)(Wih2 + (size_t)(g * OO + col0 + c) * HH + k);
                    acc[c][g] = fmaf(a3, w.w, fmaf(a2, w.z, fmaf(a1, w.y, fmaf(a0, w.x, acc[c][g]))));
                }
        }
    }
    // h2 segment: k in [max(k0,512), k1); act h2r[(k-512)*BB+lane]; W_hh2[row*OO + (k-512)]
    {
        const int ha = (k0 > 512) ? k0 : 512;
        const float* actB = h2r - 512 * BB;
        const float* Wb   = Whh2 - 512;
        for (int k = ha; k < k1; k += 4) {
            float a0 = actB[(k + 0) * BB + lane];
            float a1 = actB[(k + 1) * BB + lane];
            float a2 = actB[(k + 2) * BB + lane];
            float a3 = actB[(k + 3) * BB + lane];
            #pragma unroll
            for (int c = 0; c < NC; ++c)
                #pragma unroll
                for (int g = 0; g < 4; ++g) {
                    const float4 w = *(const float4*)(Wb + (size_t)(g * OO + col0 + c) * OO + k);
                    acc[c][g] = fmaf(a3, w.w, fmaf(a2, w.z, fmaf(a1, w.y, fmaf(a0, w.x, acc[c][g]))));
                }
        }
    }
    #pragma unroll
    for (int c = 0; c < NC; ++c)
        #pragma unroll
        for (int g = 0; g < 4; ++g) part[wv][c][g][lane] = acc[c][g];
}

template<int NC>
__device__ __forceinline__ void phaseB_epi(
    int col0, int tid, int u,
    const float* __restrict__ bih2, const float* __restrict__ bhh2,
    const float* __restrict__ c2r, float* __restrict__ c2w, float* __restrict__ h2w,
    float* __restrict__ out, float (*part)[3][4][BB])
{
    if (tid < NC * 64) {
        const int c = tid >> 6, b = tid & 63;
        const int col = col0 + c;
        float gt[4];
        #pragma unroll
        for (int g = 0; g < 4; ++g) {
            float v = part[0][c][g][b] + part[1][c][g][b] + part[2][c][g][b] + part[3][c][g][b];
            gt[g] = v + bih2[g * OO + col] + bhh2[g * OO + col];
        }
        const float ig = sigf(gt[0]);
        const float fg = sigf(gt[1]);
        const float gg = tanhf(gt[2]);
        const float og = sigf(gt[3]);
        const float cn = fg * c2r[col * BB + b] + ig * gg;
        const float hn = og * tanhf(cn);
        c2w[col * BB + b] = cn;
        h2w[col * BB + b] = hn;
        out[(size_t)b * (TT * OO) + (size_t)u * OO + col] = cn;  // per-step output = c2
    }
}

// One launch per skew index s: computes layer-1 step s (s<T) and layer-2 step s-1 (s>=1).
__global__ __launch_bounds__(256)
void step_kernel(int s,
    const float* __restrict__ data,
    const float* __restrict__ Wih1, const float* __restrict__ Whh1,
    const float* __restrict__ bih1, const float* __restrict__ bhh1,
    const float* __restrict__ Wih2, const float* __restrict__ Whh2,
    const float* __restrict__ bih2, const float* __restrict__ bhh2,
    float* __restrict__ ws, float* __restrict__ out)
{
    __shared__ float part[4][3][4][BB];   // 12 KB: [wave][col][gate][batch]
    const int tid  = threadIdx.x;
    const int wv   = tid >> 6;
    const int lane = tid & 63;            // lane == batch index
    const int blk  = blockIdx.x;
    const int pw = s & 1, pr = pw ^ 1;

    float* h1r = ws + H1_OFF + pr * H1SZ;  float* h1w = ws + H1_OFF + pw * H1SZ;
    float* c1r = ws + C1_OFF + pr * H1SZ;  float* c1w = ws + C1_OFF + pw * H1SZ;
    float* h2r = ws + H2_OFF + pw * H2SZ;  float* h2w = ws + H2_OFF + pr * H2SZ;
    float* c2r = ws + C2_OFF + pw * H2SZ;  float* c2w = ws + C2_OFF + pr * H2SZ;

    // ---------------- phase A: layer-1 step s ----------------
    if (s < TT) {
        const int col0 = blk * 2;
        float acc[2][4];
        #pragma unroll
        for (int c = 0; c < 2; ++c)
            #pragma unroll
            for (int g = 0; g < 4; ++g) acc[c][g] = 0.f;

        const int k0 = wv * 136, k1 = k0 + 136;   // K=544 = [x:32 | h1:512]

        // x segment (wave 0 only): act from data (strided per-lane), W_ih1[row*FF + k]
        if (k0 < 32) {
            const int xbase = lane * (TT * FF) + s * FF;
            for (int k = k0; k < 32; k += 4) {
                float a0 = data[xbase + k + 0];
                float a1 = data[xbase + k + 1];
                float a2 = data[xbase + k + 2];
                float a3 = data[xbase + k + 3];
                #pragma unroll
                for (int c = 0; c < 2; ++c)
                    #pragma unroll
                    for (int g = 0; g < 4; ++g) {
                        const float4 w = *(const float4*)(Wih1 + (size_t)(g * HH + col0 + c) * FF + k);
                        acc[c][g] = fmaf(a3, w.w, fmaf(a2, w.z, fmaf(a1, w.y, fmaf(a0, w.x, acc[c][g]))));
                    }
            }
        }
        // h1 segment: k in [max(k0,32), k1); act h1r[(k-32)*BB+lane]; W_hh1[row*HH + (k-32)]
        {
            const int ka = (k0 < 32) ? 32 : k0;
            const float* actB = h1r - 32 * BB;
            const float* Wb   = Whh1 - 32;
            for (int k = ka; k < k1; k += 4) {
                float a0 = actB[(k + 0) * BB + lane];
                float a1 = actB[(k + 1) * BB + lane];
                float a2 = actB[(k + 2) * BB + lane];
                float a3 = actB[(k + 3) * BB + lane];
                #pragma unroll
                for (int c = 0; c < 2; ++c)
                    #pragma unroll
                    for (int g = 0; g < 4; ++g) {
                        const float4 w = *(const float4*)(Wb + (size_t)(g * HH + col0 + c) * HH + k);
                        acc[c][g] = fmaf(a3, w.w, fmaf(a2, w.z, fmaf(a1, w.y, fmaf(a0, w.x, acc[c][g]))));
                    }
            }
        }
        #pragma unroll
        for (int c = 0; c < 2; ++c)
            #pragma unroll
            for (int g = 0; g < 4; ++g) part[wv][c][g][lane] = acc[c][g];
    }
    __syncthreads();
    if (s < TT && tid < 128) {
        const int c = tid >> 6, b = tid & 63;
        const int col = blk * 2 + c;
        float gt[4];
        #pragma unroll
        for (int g = 0; g < 4; ++g) {
            float v = part[0][c][g][b] + part[1][c][g][b] + part[2][c][g][b] + part[3][c][g][b];
            gt[g] = v + bih1[g * HH + col] + bhh1[g * HH + col];
        }
        const float ig = sigf(gt[0]);
        const float fg = sigf(gt[1]);
        const float gg = tanhf(gt[2]);
        const float og = sigf(gt[3]);
        const float cn = fg * c1r[col * BB + b] + ig * gg;
        const float hn = og * tanhf(cn);
        c1w[col * BB + b] = cn;
        h1w[col * BB + b] = hn;
    }
    __syncthreads();

    // ---------------- phase B: layer-2 step s-1 ----------------
    if (s >= 1) {
        if (blk < 168) phaseB_compute<3>(blk * 3, wv, lane, Wih2, Whh2, c1r, h2r, part);
        else           phaseB_compute<2>(504 + (blk - 168) * 2, wv, lane, Wih2, Whh2, c1r, h2r, part);
    }
    __syncthreads();
    if (s >= 1) {
        const int u = s - 1;
        if (blk < 168) phaseB_epi<3>(blk * 3, tid, u, bih2, bhh2, c2r, c2w, h2w, out, part);
        else           phaseB_epi<2>(504 + (blk - 168) * 2, tid, u, bih2, bhh2, c2r, c2w, h2w, out, part);
    }
}

extern "C" void kernel_launch(void* const* d_in, const int* in_sizes, int n_in,
                              void* d_out, int out_size, void* d_ws, size_t ws_size,
                              hipStream_t stream)
{
    const float* data = (const float*)d_in[0];
    const float* Wih1 = (const float*)d_in[1];
    const float* Whh1 = (const float*)d_in[2];
    const float* bih1 = (const float*)d_in[3];
    const float* bhh1 = (const float*)d_in[4];
    const float* Wih2 = (const float*)d_in[5];
    const float* Whh2 = (const float*)d_in[6];
    const float* bih2 = (const float*)d_in[7];
    const float* bhh2 = (const float*)d_in[8];
    float* out = (float*)d_out;
    float* ws  = (float*)d_ws;

    zero_ws<<<(WS_FLOATS + 255) / 256, 256, 0, stream>>>(ws);
    for (int s = 0; s <= TT; ++s) {
        step_kernel<<<256, 256, 0, stream>>>(s, data,
                                             Wih1, Whh1, bih1, bhh1,
                                             Wih2, Whh2, bih2, bhh2,
                                             ws, out);
    }
}

// Round 2
// 22621.167 us; speedup vs baseline: 1.0474x; 1.0474x over previous
//
#include <hip/hip_runtime.h>
#include <math.h>

#define BB 64
#define TT 512
#define FF 32
#define HH 512
#define OO 680

#define H1SZ (HH*BB)   // 32768
#define H2SZ (OO*BB)   // 43520

// ws layout (floats), ping-pong state buffers
#define H1_OFF 0
#define C1_OFF (H1_OFF + 2*H1SZ)
#define H2_OFF (C1_OFF + 2*H1SZ)
#define C2_OFF (H2_OFF + 2*H2SZ)
#define WS_FLOATS (C2_OFF + 2*H2SZ)   // 305152 floats = 1.22 MB

__global__ void zero_ws(float* ws) {
    int i = blockIdx.x * blockDim.x + threadIdx.x;
    if (i < WS_FLOATS) ws[i] = 0.f;
}

__device__ __forceinline__ float sigf(float x) { return 1.f / (1.f + expf(-x)); }

// One launch per skew index s.
// Blocks [0, 512):   layer-1 column blk, step s        (active for s < T)
// Blocks [512,1192): layer-2 column blk-512, step s-1  (active for s >= 1)
// 256 threads = 4 waves; K split 4-ways across waves; lane == batch index.
__global__ __launch_bounds__(256)
void step_kernel(int s,
    const float* __restrict__ data,
    const float* __restrict__ Wih1, const float* __restrict__ Whh1,
    const float* __restrict__ bih1, const float* __restrict__ bhh1,
    const float* __restrict__ Wih2, const float* __restrict__ Whh2,
    const float* __restrict__ bih2, const float* __restrict__ bhh2,
    float* __restrict__ ws, float* __restrict__ out)
{
    __shared__ float part[4][4][BB];   // 4 KB: [wave][gate][batch]
    const int tid  = threadIdx.x;
    const int wv   = tid >> 6;
    const int lane = tid & 63;         // batch index
    const int blk  = blockIdx.x;
    const int pw = s & 1, pr = pw ^ 1;

    float* h1r = ws + H1_OFF + pr * H1SZ;  float* h1w = ws + H1_OFF + pw * H1SZ;
    float* c1r = ws + C1_OFF + pr * H1SZ;  float* c1w = ws + C1_OFF + pw * H1SZ;
    float* h2r = ws + H2_OFF + pw * H2SZ;  float* h2w = ws + H2_OFF + pr * H2SZ;
    float* c2r = ws + C2_OFF + pw * H2SZ;  float* c2w = ws + C2_OFF + pr * H2SZ;

    if (blk < HH) {
        // ---------------- layer-1, column `col`, step s ----------------
        const int col = blk;
        if (s < TT) {
            float acc[4] = {0.f, 0.f, 0.f, 0.f};
            const int k0 = wv * 136, k1 = k0 + 136;   // K=544 = [x:32 | h1:512]

            if (k0 < FF) {  // x segment (wave 0 only)
                const int xbase = lane * (TT * FF) + s * FF;
                #pragma unroll
                for (int k = 0; k < FF; k += 4) {
                    const float a0 = data[xbase + k + 0];
                    const float a1 = data[xbase + k + 1];
                    const float a2 = data[xbase + k + 2];
                    const float a3 = data[xbase + k + 3];
                    #pragma unroll
                    for (int g = 0; g < 4; ++g) {
                        const float4 w = *(const float4*)(Wih1 + (size_t)(g * HH + col) * FF + k);
                        acc[g] = fmaf(a3, w.w, fmaf(a2, w.z, fmaf(a1, w.y, fmaf(a0, w.x, acc[g]))));
                    }
                }
            }
            {   // h1 segment
                const int ka = (k0 < FF) ? FF : k0;
                const float* actB = h1r - FF * BB;
                const float* Wb   = Whh1 - FF;
                for (int k = ka; k < k1; k += 4) {
                    const float a0 = actB[(k + 0) * BB + lane];
                    const float a1 = actB[(k + 1) * BB + lane];
                    const float a2 = actB[(k + 2) * BB + lane];
                    const float a3 = actB[(k + 3) * BB + lane];
                    #pragma unroll
                    for (int g = 0; g < 4; ++g) {
                        const float4 w = *(const float4*)(Wb + (size_t)(g * HH + col) * HH + k);
                        acc[g] = fmaf(a3, w.w, fmaf(a2, w.z, fmaf(a1, w.y, fmaf(a0, w.x, acc[g]))));
                    }
                }
            }
            #pragma unroll
            for (int g = 0; g < 4; ++g) part[wv][g][lane] = acc[g];
        }
        __syncthreads();
        if (s < TT && tid < BB) {
            const int b = tid;
            float gt[4];
            #pragma unroll
            for (int g = 0; g < 4; ++g) {
                float v = part[0][g][b] + part[1][g][b] + part[2][g][b] + part[3][g][b];
                gt[g] = v + bih1[g * HH + col] + bhh1[g * HH + col];
            }
            const float ig = sigf(gt[0]);
            const float fg = sigf(gt[1]);
            const float gg = tanhf(gt[2]);
            const float og = sigf(gt[3]);
            const float cn = fg * c1r[col * BB + b] + ig * gg;
            const float hn = og * tanhf(cn);
            c1w[col * BB + b] = cn;
            h1w[col * BB + b] = hn;
        }
    } else {
        // ---------------- layer-2, column `col`, step s-1 ----------------
        const int col = blk - HH;      // 0..679
        if (s >= 1) {
            float acc[4] = {0.f, 0.f, 0.f, 0.f};
            // K=1192 = [c1:512 | h2:680]; wave ranges {0,300,600,896,1192}
            const int k0 = (wv < 2) ? wv * 300 : 600 + (wv - 2) * 296;
            const int k1 = (wv == 0) ? 300 : (wv == 1) ? 600 : (wv == 2) ? 896 : 1192;

            {   // c1 segment
                const int cb = (k1 < HH) ? k1 : HH;
                for (int k = k0; k < cb; k += 4) {
                    const float a0 = c1r[(k + 0) * BB + lane];
                    const float a1 = c1r[(k + 1) * BB + lane];
                    const float a2 = c1r[(k + 2) * BB + lane];
                    const float a3 = c1r[(k + 3) * BB + lane];
                    #pragma unroll
                    for (int g = 0; g < 4; ++g) {
                        const float4 w = *(const float4*)(Wih2 + (size_t)(g * OO + col) * HH + k);
                        acc[g] = fmaf(a3, w.w, fmaf(a2, w.z, fmaf(a1, w.y, fmaf(a0, w.x, acc[g]))));
                    }
                }
            }
            {   // h2 segment
                const int ha = (k0 > HH) ? k0 : HH;
                const float* actB = h2r - HH * BB;
                const float* Wb   = Whh2 - HH;
                for (int k = ha; k < k1; k += 4) {
                    const float a0 = actB[(k + 0) * BB + lane];
                    const float a1 = actB[(k + 1) * BB + lane];
                    const float a2 = actB[(k + 2) * BB + lane];
                    const float a3 = actB[(k + 3) * BB + lane];
                    #pragma unroll
                    for (int g = 0; g < 4; ++g) {
                        const float4 w = *(const float4*)(Wb + (size_t)(g * OO + col) * OO + k);
                        acc[g] = fmaf(a3, w.w, fmaf(a2, w.z, fmaf(a1, w.y, fmaf(a0, w.x, acc[g]))));
                    }
                }
            }
            #pragma unroll
            for (int g = 0; g < 4; ++g) part[wv][g][lane] = acc[g];
        }
        __syncthreads();
        if (s >= 1 && tid < BB) {
            const int b = tid, u = s - 1;
            float gt[4];
            #pragma unroll
            for (int g = 0; g < 4; ++g) {
                float v = part[0][g][b] + part[1][g][b] + part[2][g][b] + part[3][g][b];
                gt[g] = v + bih2[g * OO + col] + bhh2[g * OO + col];
            }
            const float ig = sigf(gt[0]);
            const float fg = sigf(gt[1]);
            const float gg = tanhf(gt[2]);
            const float og = sigf(gt[3]);
            const float cn = fg * c2r[col * BB + b] + ig * gg;
            const float hn = og * tanhf(cn);
            c2w[col * BB + b] = cn;
            h2w[col * BB + b] = hn;
            out[(size_t)b * (TT * OO) + (size_t)u * OO + col] = cn;  // per-step output = c2
        }
    }
}

extern "C" void kernel_launch(void* const* d_in, const int* in_sizes, int n_in,
                              void* d_out, int out_size, void* d_ws, size_t ws_size,
                              hipStream_t stream)
{
    const float* data = (const float*)d_in[0];
    const float* Wih1 = (const float*)d_in[1];
    const float* Whh1 = (const float*)d_in[2];
    const float* bih1 = (const float*)d_in[3];
    const float* bhh1 = (const float*)d_in[4];
    const float* Wih2 = (const float*)d_in[5];
    const float* Whh2 = (const float*)d_in[6];
    const float* bih2 = (const float*)d_in[7];
    const float* bhh2 = (const float*)d_in[8];
    float* out = (float*)d_out;
    float* ws  = (float*)d_ws;

    zero_ws<<<(WS_FLOATS + 255) / 256, 256, 0, stream>>>(ws);
    for (int s = 0; s <= TT; ++s) {
        step_kernel<<<HH + OO, 256, 0, stream>>>(s, data,
                                                 Wih1, Whh1, bih1, bhh1,
                                                 Wih2, Whh2, bih2, bhh2,
                                                 ws, out);
    }
}